// Round 10
// baseline (412.295 us; speedup 1.0000x reference)
//
#include <hip/hip_runtime.h>
#include <math.h>

#define IN_CH   256
#define NCLS    21
#define ROIW    7
#define NPROP   128
#define BATCH   2
#define NROI    (BATCH*NPROP)        // 256
#define FEAT_DIM (IN_CH*ROIW*ROIW)   // 12544
#define HID     1024
#define NCAND   (NPROP*(NCLS-1))     // 2560 per image
#define MAXDET  100
#define SCORE_T 0.05f
#define NMS_T   0.5f
#define SPLIT1  32                   // FC1 split-K (FC2 stays 16)

// ---------------- feature transpose: [img][c][pos] -> [img][pos][c] ----------------
__global__ __launch_bounds__(256) void transpose_feat(const float* __restrict__ feat,
                                                      float* __restrict__ ft) {
    int img = blockIdx.z;
    int cb = blockIdx.y;
    int pb = blockIdx.x;
    __shared__ float t[32][33];
    int tx = threadIdx.x & 31, ty = threadIdx.x >> 5;
#pragma unroll
    for (int i = 0; i < 4; ++i) {
        int c = ty + i * 8;
        t[c][tx] = feat[(size_t)img * 262144 + (size_t)(cb * 32 + c) * 1024 + pb * 32 + tx];
    }
    __syncthreads();
#pragma unroll
    for (int i = 0; i < 4; ++i) {
        int p = ty + i * 8;
        ft[(size_t)img * 262144 + (size_t)(pb * 32 + p) * 256 + cb * 32 + tx] = t[tx][p];
    }
}

// ---------------- RoIAlign on transposed features (fully coalesced) ----------------
__global__ __launch_bounds__(256) void roi_align_tr(const float* __restrict__ ft,
                                                    const float* __restrict__ props,
                                                    float* __restrict__ out) {
    int n = blockIdx.x >> 1;
    int half = blockIdx.x & 1;
    int img = n / NPROP;
    int q0 = half ? 25 : 0;
    int nq = half ? 24 : 25;
    const float* pr = props + n * 4;
    float x1 = pr[0] * 0.03125f, y1 = pr[1] * 0.03125f;
    float x2 = pr[2] * 0.03125f, y2 = pr[3] * 0.03125f;
    float rw = fmaxf(x2 - x1, 1.0f), rh = fmaxf(y2 - y1, 1.0f);
    float bw = rw / 7.0f, bh = rh / 7.0f;
    int cg = threadIdx.x & 63;
    int qg = threadIdx.x >> 6;
    __shared__ float tile[25][260];
    const float* base = ft + (size_t)img * 262144 + cg * 4;
    for (int j = qg; j < nq; j += 4) {
        int q = q0 + j;
        int iy = q / 7, ix = q % 7;
        float ax = 0.f, ay = 0.f, az = 0.f, aw = 0.f;
#pragma unroll
        for (int s = 0; s < 4; ++s) {
            int sy = s >> 1, sx = s & 1;
            float gy = (float)iy + ((float)sy + 0.5f) / 2.0f;
            float gx = (float)ix + ((float)sx + 0.5f) / 2.0f;
            float y = y1 + gy * bh;
            float x = x1 + gx * bw;
            bool inb = (y >= -1.0f) && (y <= 32.0f) && (x >= -1.0f) && (x <= 32.0f);
            float yc = fminf(fmaxf(y, 0.0f), 31.0f);
            float xc = fminf(fmaxf(x, 0.0f), 31.0f);
            float y0f = floorf(yc), x0f = floorf(xc);
            int y0 = (int)y0f, x0i = (int)x0f;
            int y1i = min(y0 + 1, 31), x1i = min(x0i + 1, 31);
            float ly = yc - y0f, lx = xc - x0f;
            float hy = 1.0f - ly, hx = 1.0f - lx;
            float wg = inb ? 1.0f : 0.0f;
            float w00 = hy * hx * wg, w01 = hy * lx * wg, w10 = ly * hx * wg, w11 = ly * lx * wg;
            float4 f00 = *(const float4*)(base + (size_t)(y0 * 32 + x0i) * 256);
            float4 f01 = *(const float4*)(base + (size_t)(y0 * 32 + x1i) * 256);
            float4 f10 = *(const float4*)(base + (size_t)(y1i * 32 + x0i) * 256);
            float4 f11 = *(const float4*)(base + (size_t)(y1i * 32 + x1i) * 256);
            ax += w00 * f00.x + w01 * f01.x + w10 * f10.x + w11 * f11.x;
            ay += w00 * f00.y + w01 * f01.y + w10 * f10.y + w11 * f11.y;
            az += w00 * f00.z + w01 * f01.z + w10 * f10.z + w11 * f11.z;
            aw += w00 * f00.w + w01 * f01.w + w10 * f10.w + w11 * f11.w;
        }
        *(float4*)&tile[j][cg * 4] = make_float4(ax * 0.25f, ay * 0.25f, az * 0.25f, aw * 0.25f);
    }
    __syncthreads();
    float* ob = out + (size_t)n * FEAT_DIM + q0;
    int tid = threadIdx.x;
    if (half == 0) {
        for (int i = tid; i < 256 * 25; i += 256) {
            int c = i / 25, ql = i % 25;
            ob[c * 49 + ql] = tile[ql][c];
        }
    } else {
        for (int i = tid; i < 256 * 24; i += 256) {
            int c = i / 24, ql = i % 24;
            ob[c * 49 + ql] = tile[ql][c];
        }
    }
}

// ---------------- GEMM (R4-exact, proven 92us): 128x128, 8x8, GBK=8, 1-deep ----------------
#define GBM 128
#define GBN 128
#define GBK 8
__global__ __launch_bounds__(256, 2) void gemm_tn_part(const float* __restrict__ A,
                                                       const float* __restrict__ Wt,
                                                       float* __restrict__ Cp,
                                                       int Nr, int Mo, int K) {
    const int S = gridDim.z;
    const int kchunk = K / S;
    const int k0 = blockIdx.z * kchunk;
    const int n0 = blockIdx.y * GBM;
    const int j0 = blockIdx.x * GBN;
    __shared__ float As[GBK][GBM + 4];
    __shared__ float Ws[GBK][GBN + 4];
    const int tid = threadIdx.x;
    const int tx = tid & 15;
    const int ty = tid >> 4;
    const int r0 = ty << 2;           // rows r0..r0+3 and r0+64..r0+67
    const int c0 = tx << 2;           // cols c0..c0+3 and c0+64..c0+67
    const int srow = tid >> 1;            // 0..127
    const int skk  = (tid & 1) << 2;      // 0,4
    float acc[8][8];
#pragma unroll
    for (int r = 0; r < 8; ++r)
#pragma unroll
        for (int c = 0; c < 8; ++c) acc[r][c] = 0.0f;

    const int iters = kchunk / GBK;   // FC1: 392/8=49, FC2: 64/8=8
    const float* Abase = A + (size_t)(n0 + srow) * K + skk;
    const float* Wbase = Wt + (size_t)(j0 + srow) * K + skk;
    float4 pa = *(const float4*)(Abase + k0);
    float4 pw = *(const float4*)(Wbase + k0);

#pragma unroll 1
    for (int it = 0; it < iters; ++it) {
        __syncthreads();
        As[skk + 0][srow] = pa.x; As[skk + 1][srow] = pa.y;
        As[skk + 2][srow] = pa.z; As[skk + 3][srow] = pa.w;
        Ws[skk + 0][srow] = pw.x; Ws[skk + 1][srow] = pw.y;
        Ws[skk + 2][srow] = pw.z; Ws[skk + 3][srow] = pw.w;
        __syncthreads();
        if (it + 1 < iters) {
            int kc = k0 + (it + 1) * GBK;
            pa = *(const float4*)(Abase + kc);
            pw = *(const float4*)(Wbase + kc);
        }
        float4 fa0[2], fa1[2], fw0[2], fw1[2];
        fa0[0] = *(const float4*)&As[0][r0];
        fa1[0] = *(const float4*)&As[0][r0 + 64];
        fw0[0] = *(const float4*)&Ws[0][c0];
        fw1[0] = *(const float4*)&Ws[0][c0 + 64];
#pragma unroll
        for (int k = 0; k < GBK; ++k) {
            const int cur = k & 1, nxt = cur ^ 1;
            if (k + 1 < GBK) {
                fa0[nxt] = *(const float4*)&As[k + 1][r0];
                fa1[nxt] = *(const float4*)&As[k + 1][r0 + 64];
                fw0[nxt] = *(const float4*)&Ws[k + 1][c0];
                fw1[nxt] = *(const float4*)&Ws[k + 1][c0 + 64];
            }
            float a[8] = {fa0[cur].x, fa0[cur].y, fa0[cur].z, fa0[cur].w,
                          fa1[cur].x, fa1[cur].y, fa1[cur].z, fa1[cur].w};
            float w[8] = {fw0[cur].x, fw0[cur].y, fw0[cur].z, fw0[cur].w,
                          fw1[cur].x, fw1[cur].y, fw1[cur].z, fw1[cur].w};
#pragma unroll
            for (int r = 0; r < 8; ++r)
#pragma unroll
                for (int c = 0; c < 8; ++c)
                    acc[r][c] = fmaf(a[r], w[c], acc[r][c]);
        }
    }
#pragma unroll
    for (int r = 0; r < 8; ++r) {
        int gr = n0 + ((r < 4) ? (r0 + r) : (r0 + 64 + r - 4));
        float* o = Cp + ((size_t)blockIdx.z * Nr + gr) * Mo + j0;
        *(float4*)(o + c0)      = make_float4(acc[r][0], acc[r][1], acc[r][2], acc[r][3]);
        *(float4*)(o + c0 + 64) = make_float4(acc[r][4], acc[r][5], acc[r][6], acc[r][7]);
    }
}

// ---------------- reduce split-K partials + bias + relu (4-way split-S) ----------------
// 4 threads per output float4 (parts = quarters of S), shfl_xor combine.
// Fixes the old version's 1-float4-per-thread 32-dependent-load latency chain
// (grid was 256 blocks = 1 block/CU). Tree ((q0+q1)+(q2+q3)) vs fold-left:
// smaller perturbation than R4's accepted chunk change.
__global__ __launch_bounds__(256) void reduce_bias_relu(const float* __restrict__ Cp,
                                                        const float* __restrict__ bias,
                                                        float* __restrict__ X,
                                                        int Nr, int Mo, int S) {
    int gid = blockIdx.x * 256 + threadIdx.x;
    int total4 = (Nr * Mo) >> 2;
    int e4 = gid >> 2;
    int part = gid & 3;
    if (e4 >= total4) return;
    int e = e4 << 2;
    int j = e % Mo;
    int q = S >> 2;
    float4 s = make_float4(0.f, 0.f, 0.f, 0.f);
    for (int ss = part * q; ss < (part + 1) * q; ++ss) {
        float4 c = *(const float4*)(Cp + (size_t)ss * Nr * Mo + e);
        s.x += c.x; s.y += c.y; s.z += c.z; s.w += c.w;
    }
#pragma unroll
    for (int m = 1; m < 4; m <<= 1) {
        s.x += __shfl_xor(s.x, m, 64);
        s.y += __shfl_xor(s.y, m, 64);
        s.z += __shfl_xor(s.z, m, 64);
        s.w += __shfl_xor(s.w, m, 64);
    }
    if (part == 0) {
        float4 b = *(const float4*)(bias + j);
        s.x = fmaxf(s.x + b.x, 0.f); s.y = fmaxf(s.y + b.y, 0.f);
        s.z = fmaxf(s.z + b.z, 0.f); s.w = fmaxf(s.w + b.w, 0.f);
        *(float4*)(X + e) = s;
    }
}

// ---------------- fused: reduce2 + heads + softmax + decode/clip/key ----------------
__global__ __launch_bounds__(256) void heads_cand_k(const float* __restrict__ Cp2,
                                                    const float* __restrict__ b2,
                                                    const float* __restrict__ Wc, const float* __restrict__ bc,
                                                    const float* __restrict__ Wb, const float* __restrict__ bb,
                                                    const float* __restrict__ props,
                                                    const int* __restrict__ img_sizes,
                                                    float* __restrict__ cbox,
                                                    float* __restrict__ csc,
                                                    unsigned long long* __restrict__ ckey) {
    int n = blockIdx.x;
    int tid = threadIdx.x;
    __shared__ float xs[HID];
    __shared__ float lg[NCLS];
    __shared__ float bs[84];
    __shared__ float ssum;
    {
        int e = n * HID + tid * 4;
        float4 s = make_float4(0.f, 0.f, 0.f, 0.f);
#pragma unroll
        for (int ss = 0; ss < 16; ++ss) {
            float4 c = *(const float4*)(Cp2 + (size_t)ss * (NROI * HID) + e);
            s.x += c.x; s.y += c.y; s.z += c.z; s.w += c.w;
        }
        float4 b = *(const float4*)(b2 + tid * 4);
        s.x = fmaxf(s.x + b.x, 0.f); s.y = fmaxf(s.y + b.y, 0.f);
        s.z = fmaxf(s.z + b.z, 0.f); s.w = fmaxf(s.w + b.w, 0.f);
        *(float4*)&xs[tid * 4] = s;
    }
    __syncthreads();
    int wave = tid >> 6, lane = tid & 63;
    for (int h = wave; h < 105; h += 4) {
        const float* w = (h < 21) ? (Wc + (size_t)h * HID) : (Wb + (size_t)(h - 21) * HID);
        float acc = 0.0f;
#pragma unroll
        for (int k0 = 0; k0 < HID; k0 += 256) {
            float4 wv = *(const float4*)(w + k0 + lane * 4);
            float4 xv = *(const float4*)&xs[k0 + lane * 4];
            acc = fmaf(wv.x, xv.x, acc);
            acc = fmaf(wv.y, xv.y, acc);
            acc = fmaf(wv.z, xv.z, acc);
            acc = fmaf(wv.w, xv.w, acc);
        }
#pragma unroll
        for (int m = 32; m; m >>= 1) acc += __shfl_xor(acc, m, 64);
        if (lane == 0) {
            if (h < 21) lg[h] = acc + bc[h];
            else bs[h - 21] = acc + bb[h - 21];
        }
    }
    __syncthreads();
    if (tid == 0) {
        float m = lg[0];
        for (int c = 1; c < 21; ++c) m = fmaxf(m, lg[c]);
        float s = 0.0f;
        for (int c = 0; c < 21; ++c) { float e = expf(lg[c] - m); lg[c] = e; s += e; }
        ssum = s;
    }
    __syncthreads();
    if (tid < 20) {
        int c = tid + 1;
        int img = n / NPROP;
        float s = lg[c] / ssum;
        const float* pr = props + n * 4;
        float pw = pr[2] - pr[0], ph = pr[3] - pr[1];
        float px = pr[0] + pw * 0.5f, py = pr[1] + ph * 0.5f;
        const float* d = &bs[c * 4];
        float cx = px + d[0] * pw;
        float cy = py + d[1] * ph;
        float w = pw * expf(d[2]);
        float h = ph * expf(d[3]);
        float bx1 = cx - w * 0.5f, by1 = cy - h * 0.5f, bx2 = cx + w * 0.5f, by2 = cy + h * 0.5f;
        float Wi = (float)img_sizes[img * 2 + 1], Hi = (float)img_sizes[img * 2 + 0];
        bx1 = fminf(fmaxf(bx1, 0.f), Wi); by1 = fminf(fmaxf(by1, 0.f), Hi);
        bx2 = fminf(fmaxf(bx2, 0.f), Wi); by2 = fminf(fmaxf(by2, 0.f), Hi);
        int t = n * 20 + tid;                 // == img*NCAND + p*20 + (c-1)
        *(float4*)(cbox + (size_t)t * 4) = make_float4(bx1, by1, bx2, by2);
        csc[t] = s;
        bool valid = s > SCORE_T;
        unsigned int sb = __float_as_uint(s);
        int m = t - img * NCAND;
        ckey[t] = valid ? (((unsigned long long)sb << 32) | (unsigned int)(NCAND - 1 - m)) : 0ull;
    }
}

// ---------------- fused tail: rank + per-class NMS + top-100 writer ----------------
// One block per image (2 blocks x 1024 threads). Replaces rank_k(80) -> nms_k(40)
// -> write_k(2): same key/rank logic, same per-class greedy-NMS semantics (one
// class per wave, intra-wave lockstep replaces the old 64-thread-block barriers),
// same ascending-sorted-position output order. Saves 2 launches + 2 tiny-grid
// latency floors. Sorted arrays flow through global scratch (sbox/ssc/smg);
// __syncthreads orders the block's own global writes/reads (single CU -> same L2).
__global__ __launch_bounds__(1024) void tail_k(const float* __restrict__ cbox,
                                               const float* __restrict__ csc,
                                               const unsigned long long* __restrict__ ckey,
                                               float* __restrict__ sbox,
                                               float* __restrict__ ssc,
                                               int* __restrict__ smg,
                                               float* __restrict__ out) {
    const int img = blockIdx.x;
    const int tid = threadIdx.x;
    const int base = img * NCAND;

    __shared__ union {
        unsigned long long keys[NCAND];                                   // phase 1 (20KB)
        struct { float x1[20][128], y1[20][128], x2[20][128], y2[20][128]; } c;  // phase 2 (40KB)
    } u;
    __shared__ short cpos[20][128];          // 5KB
    __shared__ unsigned char ckeepA[20][128];// 2.5KB
    __shared__ unsigned char smcls[NCAND];   // 2.5KB
    __shared__ unsigned char keepS[NCAND];   // 2.5KB
    __shared__ int Vs;
    __shared__ int scanA[1024], scanB[1024]; // 8KB

    if (tid == 0) Vs = 0;
    for (int j2 = tid; j2 < NCAND; j2 += 1024) u.keys[j2] = ckey[base + j2];
    __syncthreads();

    // ---- phase 1: rank (count of strictly-greater keys), scatter sorted to global
    int myV = 0;
    for (int m = tid; m < NCAND; m += 1024) {
        float s = csc[base + m];
        if (s > SCORE_T) {
            unsigned long long mykey = u.keys[m];
            const ulonglong2* kp = (const ulonglong2*)u.keys;
            int r = 0;
#pragma unroll 4
            for (int j2 = 0; j2 < NCAND / 2; ++j2) {
                ulonglong2 kk = kp[j2];
                r += (kk.x > mykey) ? 1 : 0;
                r += (kk.y > mykey) ? 1 : 0;
            }
            int o = base + r;
            *(float4*)(sbox + (size_t)o * 4) = *(const float4*)(cbox + (size_t)(base + m) * 4);
            ssc[o] = s;
            smg[o] = m;
            ++myV;
        }
    }
    atomicAdd(&Vs, myV);
    __syncthreads();                       // sorted arrays + Vs ready
    const int V = Vs;
    for (int p = tid; p < V; p += 1024) smcls[p] = (unsigned char)(smg[base + p] % 20);
    __syncthreads();                       // smcls ready; u.keys dead -> u.c reusable

    // ---- phase 2: per-class greedy NMS; wave w handles classes w, w+16
    const int wv = tid >> 6, lane = tid & 63;
    for (int ci = wv; ci < 20; ci += 16) {
        int cnt = 0;
        for (int p0 = 0; p0 < V; p0 += 64) {
            int p = p0 + lane;
            bool pred = (p < V) && (smcls[p] == (unsigned char)ci);
            unsigned long long mask = __ballot(pred);
            if (pred) {
                int idx = cnt + (int)__popcll(mask & ((1ull << lane) - 1ull));
                const float* bx = sbox + (size_t)(base + p) * 4;
                u.c.x1[ci][idx] = bx[0]; u.c.y1[ci][idx] = bx[1];
                u.c.x2[ci][idx] = bx[2]; u.c.y2[ci][idx] = bx[3];
                cpos[ci][idx] = (short)p;
            }
            cnt += (int)__popcll(mask);
        }
        for (int j2 = lane; j2 < 128; j2 += 64) ckeepA[ci][j2] = 1;
        for (int i = 0; i < cnt; ++i) {
            if (ckeepA[ci][i] == 0) continue;
            float X1 = u.c.x1[ci][i], Y1 = u.c.y1[ci][i];
            float X2 = u.c.x2[ci][i], Y2 = u.c.y2[ci][i];
            float ai = (X2 - X1) * (Y2 - Y1);
            for (int j2 = i + 1 + lane; j2 < cnt; j2 += 64) {
                if (ckeepA[ci][j2]) {
                    float xi1 = fmaxf(X1, u.c.x1[ci][j2]);
                    float yi1 = fmaxf(Y1, u.c.y1[ci][j2]);
                    float xi2 = fminf(X2, u.c.x2[ci][j2]);
                    float yi2 = fminf(Y2, u.c.y2[ci][j2]);
                    float inter = fmaxf(xi2 - xi1, 0.f) * fmaxf(yi2 - yi1, 0.f);
                    float aj = (u.c.x2[ci][j2] - u.c.x1[ci][j2]) * (u.c.y2[ci][j2] - u.c.y1[ci][j2]);
                    float iou = inter / (ai + aj - inter + 1e-9f);
                    if (iou > NMS_T) ckeepA[ci][j2] = 0;
                }
            }
        }
        for (int j2 = lane; j2 < cnt; j2 += 64) keepS[cpos[ci][j2]] = ckeepA[ci][j2];
    }
    __syncthreads();

    // ---- phase 3: zero outputs, block prefix-scan over keepS, emit top-100
    float* ob = out + img * MAXDET * 4;
    float* os = out + BATCH * MAXDET * 4 + img * MAXDET;
    float* ol = out + BATCH * MAXDET * 5 + img * MAXDET;
    for (int i = tid; i < MAXDET * 4; i += 1024) ob[i] = 0.0f;
    for (int i = tid; i < MAXDET; i += 1024) { os[i] = 0.0f; ol[i] = 0.0f; }
    int chunk = (V + 1023) >> 10;
    int lo = tid * chunk, hi = min(lo + chunk, V);
    int cnt2 = 0;
    for (int p = lo; p < hi; ++p) cnt2 += keepS[p];
    scanA[tid] = cnt2;
    __syncthreads();
    int* src = scanA; int* dst = scanB;
    for (int off = 1; off < 1024; off <<= 1) {
        int v = src[tid] + ((tid >= off) ? src[tid - off] : 0);
        dst[tid] = v;
        __syncthreads();
        int* t = src; src = dst; dst = t;
    }
    int r = (tid > 0) ? src[tid - 1] : 0;   // exclusive prefix
    for (int p = lo; p < hi; ++p) {
        if (keepS[p]) {
            if (r < MAXDET) {
                const float* bx = sbox + (size_t)(base + p) * 4;
                ob[r * 4 + 0] = bx[0]; ob[r * 4 + 1] = bx[1];
                ob[r * 4 + 2] = bx[2]; ob[r * 4 + 3] = bx[3];
                os[r] = ssc[base + p];
                ol[r] = (float)(smg[base + p] % 20 + 1);
            }
            ++r;
        }
    }
}

extern "C" void kernel_launch(void* const* d_in, const int* in_sizes, int n_in,
                              void* d_out, int out_size, void* d_ws, size_t ws_size,
                              hipStream_t stream) {
    const float* features  = (const float*)d_in[0];
    const float* proposals = (const float*)d_in[1];
    const int*   img_sizes = (const int*)d_in[2];
    const float* W1 = (const float*)d_in[3];
    const float* b1 = (const float*)d_in[4];
    const float* W2 = (const float*)d_in[5];
    const float* b2 = (const float*)d_in[6];
    const float* Wc = (const float*)d_in[7];
    const float* bc = (const float*)d_in[8];
    const float* Wb = (const float*)d_in[9];
    const float* bb = (const float*)d_in[10];
    float* out = (float*)d_out;

    float* ws = (float*)d_ws;
    float* roi   = ws;                        // 256*12544 = 3,211,264
    float* x1    = roi + 3211264;             // 262,144
    float* cpart = x1 + 262144;               // SPLIT1 * 262,144 (FC2 uses first 16 slices)
    float* featT = cpart;                     // aliases cpart: dead before FC1 writes it
    float* cbox  = cpart + (size_t)SPLIT1 * 262144;   // 20480
    float* csc   = cbox + 20480;              // 5120
    unsigned long long* ckey = (unsigned long long*)(csc + 5120);  // 5120 u64
    float* sbox  = csc + 5120 + 10240;        // 20480 (tail_k scratch)
    float* ssc   = sbox + 20480;              // 5120
    int*   smg   = (int*)(ssc + 5120);        // 5120

    hipLaunchKernelGGL(transpose_feat, dim3(32, 8, 2), dim3(256), 0, stream, features, featT);
    hipLaunchKernelGGL(roi_align_tr, dim3(NROI * 2), dim3(256), 0, stream, featT, proposals, roi);
    // FC1: 256 x 12544 -> 1024, tile 128x128, split-K=32 -> 512 blocks (2/CU)
    hipLaunchKernelGGL(gemm_tn_part, dim3(8, 2, SPLIT1), dim3(256), 0, stream, roi, W1, cpart, NROI, HID, FEAT_DIM);
    // reduce: 4 threads per output float4 -> 1024 blocks
    hipLaunchKernelGGL(reduce_bias_relu, dim3(1024), dim3(256), 0, stream, cpart, b1, x1, NROI, HID, SPLIT1);
    // FC2: 256 x 1024 -> 1024, split-K=16 (reduced inside heads_cand_k, order unchanged)
    hipLaunchKernelGGL(gemm_tn_part, dim3(8, 2, 16), dim3(256), 0, stream, x1, W2, cpart, NROI, HID, HID);
    hipLaunchKernelGGL(heads_cand_k, dim3(NROI), dim3(256), 0, stream, cpart, b2, Wc, bc, Wb, bb,
                       proposals, img_sizes, cbox, csc, ckey);
    hipLaunchKernelGGL(tail_k, dim3(BATCH), dim3(1024), 0, stream, cbox, csc, ckey, sbox, ssc, smg, out);
}

// Round 11
// 315.364 us; speedup vs baseline: 1.3074x; 1.3074x over previous
//
#include <hip/hip_runtime.h>
#include <math.h>

#define IN_CH   256
#define NCLS    21
#define ROIW    7
#define NPROP   128
#define BATCH   2
#define NROI    (BATCH*NPROP)        // 256
#define FEAT_DIM (IN_CH*ROIW*ROIW)   // 12544
#define HID     1024
#define NCAND   (NPROP*(NCLS-1))     // 2560 per image
#define MAXDET  100
#define SCORE_T 0.05f
#define NMS_T   0.5f
#define SPLIT1  32                   // FC1 split-K (FC2 stays 16)

// ---------------- feature transpose: [img][c][pos] -> [img][pos][c] ----------------
__global__ __launch_bounds__(256) void transpose_feat(const float* __restrict__ feat,
                                                      float* __restrict__ ft) {
    int img = blockIdx.z;
    int cb = blockIdx.y;
    int pb = blockIdx.x;
    __shared__ float t[32][33];
    int tx = threadIdx.x & 31, ty = threadIdx.x >> 5;
#pragma unroll
    for (int i = 0; i < 4; ++i) {
        int c = ty + i * 8;
        t[c][tx] = feat[(size_t)img * 262144 + (size_t)(cb * 32 + c) * 1024 + pb * 32 + tx];
    }
    __syncthreads();
#pragma unroll
    for (int i = 0; i < 4; ++i) {
        int p = ty + i * 8;
        ft[(size_t)img * 262144 + (size_t)(pb * 32 + p) * 256 + cb * 32 + tx] = t[tx][p];
    }
}

// ---------------- RoIAlign on transposed features (fully coalesced) ----------------
__global__ __launch_bounds__(256) void roi_align_tr(const float* __restrict__ ft,
                                                    const float* __restrict__ props,
                                                    float* __restrict__ out) {
    int n = blockIdx.x >> 1;
    int half = blockIdx.x & 1;
    int img = n / NPROP;
    int q0 = half ? 25 : 0;
    int nq = half ? 24 : 25;
    const float* pr = props + n * 4;
    float x1 = pr[0] * 0.03125f, y1 = pr[1] * 0.03125f;
    float x2 = pr[2] * 0.03125f, y2 = pr[3] * 0.03125f;
    float rw = fmaxf(x2 - x1, 1.0f), rh = fmaxf(y2 - y1, 1.0f);
    float bw = rw / 7.0f, bh = rh / 7.0f;
    int cg = threadIdx.x & 63;
    int qg = threadIdx.x >> 6;
    __shared__ float tile[25][260];
    const float* base = ft + (size_t)img * 262144 + cg * 4;
    for (int j = qg; j < nq; j += 4) {
        int q = q0 + j;
        int iy = q / 7, ix = q % 7;
        float ax = 0.f, ay = 0.f, az = 0.f, aw = 0.f;
#pragma unroll
        for (int s = 0; s < 4; ++s) {
            int sy = s >> 1, sx = s & 1;
            float gy = (float)iy + ((float)sy + 0.5f) / 2.0f;
            float gx = (float)ix + ((float)sx + 0.5f) / 2.0f;
            float y = y1 + gy * bh;
            float x = x1 + gx * bw;
            bool inb = (y >= -1.0f) && (y <= 32.0f) && (x >= -1.0f) && (x <= 32.0f);
            float yc = fminf(fmaxf(y, 0.0f), 31.0f);
            float xc = fminf(fmaxf(x, 0.0f), 31.0f);
            float y0f = floorf(yc), x0f = floorf(xc);
            int y0 = (int)y0f, x0i = (int)x0f;
            int y1i = min(y0 + 1, 31), x1i = min(x0i + 1, 31);
            float ly = yc - y0f, lx = xc - x0f;
            float hy = 1.0f - ly, hx = 1.0f - lx;
            float wg = inb ? 1.0f : 0.0f;
            float w00 = hy * hx * wg, w01 = hy * lx * wg, w10 = ly * hx * wg, w11 = ly * lx * wg;
            float4 f00 = *(const float4*)(base + (size_t)(y0 * 32 + x0i) * 256);
            float4 f01 = *(const float4*)(base + (size_t)(y0 * 32 + x1i) * 256);
            float4 f10 = *(const float4*)(base + (size_t)(y1i * 32 + x0i) * 256);
            float4 f11 = *(const float4*)(base + (size_t)(y1i * 32 + x1i) * 256);
            ax += w00 * f00.x + w01 * f01.x + w10 * f10.x + w11 * f11.x;
            ay += w00 * f00.y + w01 * f01.y + w10 * f10.y + w11 * f11.y;
            az += w00 * f00.z + w01 * f01.z + w10 * f10.z + w11 * f11.z;
            aw += w00 * f00.w + w01 * f01.w + w10 * f10.w + w11 * f11.w;
        }
        *(float4*)&tile[j][cg * 4] = make_float4(ax * 0.25f, ay * 0.25f, az * 0.25f, aw * 0.25f);
    }
    __syncthreads();
    float* ob = out + (size_t)n * FEAT_DIM + q0;
    int tid = threadIdx.x;
    if (half == 0) {
        for (int i = tid; i < 256 * 25; i += 256) {
            int c = i / 25, ql = i % 25;
            ob[c * 49 + ql] = tile[ql][c];
        }
    } else {
        for (int i = tid; i < 256 * 24; i += 256) {
            int c = i / 24, ql = i % 24;
            ob[c * 49 + ql] = tile[ql][c];
        }
    }
}

// ---------------- GEMM (R4-exact, proven 92us): 128x128, 8x8, GBK=8, 1-deep ----------------
#define GBM 128
#define GBN 128
#define GBK 8
__global__ __launch_bounds__(256, 2) void gemm_tn_part(const float* __restrict__ A,
                                                       const float* __restrict__ Wt,
                                                       float* __restrict__ Cp,
                                                       int Nr, int Mo, int K) {
    const int S = gridDim.z;
    const int kchunk = K / S;
    const int k0 = blockIdx.z * kchunk;
    const int n0 = blockIdx.y * GBM;
    const int j0 = blockIdx.x * GBN;
    __shared__ float As[GBK][GBM + 4];
    __shared__ float Ws[GBK][GBN + 4];
    const int tid = threadIdx.x;
    const int tx = tid & 15;
    const int ty = tid >> 4;
    const int r0 = ty << 2;           // rows r0..r0+3 and r0+64..r0+67
    const int c0 = tx << 2;           // cols c0..c0+3 and c0+64..c0+67
    const int srow = tid >> 1;            // 0..127
    const int skk  = (tid & 1) << 2;      // 0,4
    float acc[8][8];
#pragma unroll
    for (int r = 0; r < 8; ++r)
#pragma unroll
        for (int c = 0; c < 8; ++c) acc[r][c] = 0.0f;

    const int iters = kchunk / GBK;   // FC1: 392/8=49, FC2: 64/8=8
    const float* Abase = A + (size_t)(n0 + srow) * K + skk;
    const float* Wbase = Wt + (size_t)(j0 + srow) * K + skk;
    float4 pa = *(const float4*)(Abase + k0);
    float4 pw = *(const float4*)(Wbase + k0);

#pragma unroll 1
    for (int it = 0; it < iters; ++it) {
        __syncthreads();
        As[skk + 0][srow] = pa.x; As[skk + 1][srow] = pa.y;
        As[skk + 2][srow] = pa.z; As[skk + 3][srow] = pa.w;
        Ws[skk + 0][srow] = pw.x; Ws[skk + 1][srow] = pw.y;
        Ws[skk + 2][srow] = pw.z; Ws[skk + 3][srow] = pw.w;
        __syncthreads();
        if (it + 1 < iters) {
            int kc = k0 + (it + 1) * GBK;
            pa = *(const float4*)(Abase + kc);
            pw = *(const float4*)(Wbase + kc);
        }
        float4 fa0[2], fa1[2], fw0[2], fw1[2];
        fa0[0] = *(const float4*)&As[0][r0];
        fa1[0] = *(const float4*)&As[0][r0 + 64];
        fw0[0] = *(const float4*)&Ws[0][c0];
        fw1[0] = *(const float4*)&Ws[0][c0 + 64];
#pragma unroll
        for (int k = 0; k < GBK; ++k) {
            const int cur = k & 1, nxt = cur ^ 1;
            if (k + 1 < GBK) {
                fa0[nxt] = *(const float4*)&As[k + 1][r0];
                fa1[nxt] = *(const float4*)&As[k + 1][r0 + 64];
                fw0[nxt] = *(const float4*)&Ws[k + 1][c0];
                fw1[nxt] = *(const float4*)&Ws[k + 1][c0 + 64];
            }
            float a[8] = {fa0[cur].x, fa0[cur].y, fa0[cur].z, fa0[cur].w,
                          fa1[cur].x, fa1[cur].y, fa1[cur].z, fa1[cur].w};
            float w[8] = {fw0[cur].x, fw0[cur].y, fw0[cur].z, fw0[cur].w,
                          fw1[cur].x, fw1[cur].y, fw1[cur].z, fw1[cur].w};
#pragma unroll
            for (int r = 0; r < 8; ++r)
#pragma unroll
                for (int c = 0; c < 8; ++c)
                    acc[r][c] = fmaf(a[r], w[c], acc[r][c]);
        }
    }
#pragma unroll
    for (int r = 0; r < 8; ++r) {
        int gr = n0 + ((r < 4) ? (r0 + r) : (r0 + 64 + r - 4));
        float* o = Cp + ((size_t)blockIdx.z * Nr + gr) * Mo + j0;
        *(float4*)(o + c0)      = make_float4(acc[r][0], acc[r][1], acc[r][2], acc[r][3]);
        *(float4*)(o + c0 + 64) = make_float4(acc[r][4], acc[r][5], acc[r][6], acc[r][7]);
    }
}

// ---------------- reduce split-K partials + bias + relu (4-way split-S, verified R9) ----------------
__global__ __launch_bounds__(256) void reduce_bias_relu(const float* __restrict__ Cp,
                                                        const float* __restrict__ bias,
                                                        float* __restrict__ X,
                                                        int Nr, int Mo, int S) {
    int gid = blockIdx.x * 256 + threadIdx.x;
    int total4 = (Nr * Mo) >> 2;
    int e4 = gid >> 2;
    int part = gid & 3;
    if (e4 >= total4) return;
    int e = e4 << 2;
    int j = e % Mo;
    int q = S >> 2;
    float4 s = make_float4(0.f, 0.f, 0.f, 0.f);
    for (int ss = part * q; ss < (part + 1) * q; ++ss) {
        float4 c = *(const float4*)(Cp + (size_t)ss * Nr * Mo + e);
        s.x += c.x; s.y += c.y; s.z += c.z; s.w += c.w;
    }
#pragma unroll
    for (int m = 1; m < 4; m <<= 1) {
        s.x += __shfl_xor(s.x, m, 64);
        s.y += __shfl_xor(s.y, m, 64);
        s.z += __shfl_xor(s.z, m, 64);
        s.w += __shfl_xor(s.w, m, 64);
    }
    if (part == 0) {
        float4 b = *(const float4*)(bias + j);
        s.x = fmaxf(s.x + b.x, 0.f); s.y = fmaxf(s.y + b.y, 0.f);
        s.z = fmaxf(s.z + b.z, 0.f); s.w = fmaxf(s.w + b.w, 0.f);
        *(float4*)(X + e) = s;
    }
}

// ---------------- fused: reduce2 + heads + softmax + decode/clip/key ----------------
__global__ __launch_bounds__(256) void heads_cand_k(const float* __restrict__ Cp2,
                                                    const float* __restrict__ b2,
                                                    const float* __restrict__ Wc, const float* __restrict__ bc,
                                                    const float* __restrict__ Wb, const float* __restrict__ bb,
                                                    const float* __restrict__ props,
                                                    const int* __restrict__ img_sizes,
                                                    float* __restrict__ cbox,
                                                    float* __restrict__ csc,
                                                    unsigned long long* __restrict__ ckey,
                                                    int* __restrict__ vcount) {
    int n = blockIdx.x;
    int tid = threadIdx.x;
    if (n == 0 && tid < 2) vcount[tid] = 0;
    __shared__ float xs[HID];
    __shared__ float lg[NCLS];
    __shared__ float bs[84];
    __shared__ float ssum;
    {
        int e = n * HID + tid * 4;
        float4 s = make_float4(0.f, 0.f, 0.f, 0.f);
#pragma unroll
        for (int ss = 0; ss < 16; ++ss) {
            float4 c = *(const float4*)(Cp2 + (size_t)ss * (NROI * HID) + e);
            s.x += c.x; s.y += c.y; s.z += c.z; s.w += c.w;
        }
        float4 b = *(const float4*)(b2 + tid * 4);
        s.x = fmaxf(s.x + b.x, 0.f); s.y = fmaxf(s.y + b.y, 0.f);
        s.z = fmaxf(s.z + b.z, 0.f); s.w = fmaxf(s.w + b.w, 0.f);
        *(float4*)&xs[tid * 4] = s;
    }
    __syncthreads();
    int wave = tid >> 6, lane = tid & 63;
    for (int h = wave; h < 105; h += 4) {
        const float* w = (h < 21) ? (Wc + (size_t)h * HID) : (Wb + (size_t)(h - 21) * HID);
        float acc = 0.0f;
#pragma unroll
        for (int k0 = 0; k0 < HID; k0 += 256) {
            float4 wv = *(const float4*)(w + k0 + lane * 4);
            float4 xv = *(const float4*)&xs[k0 + lane * 4];
            acc = fmaf(wv.x, xv.x, acc);
            acc = fmaf(wv.y, xv.y, acc);
            acc = fmaf(wv.z, xv.z, acc);
            acc = fmaf(wv.w, xv.w, acc);
        }
#pragma unroll
        for (int m = 32; m; m >>= 1) acc += __shfl_xor(acc, m, 64);
        if (lane == 0) {
            if (h < 21) lg[h] = acc + bc[h];
            else bs[h - 21] = acc + bb[h - 21];
        }
    }
    __syncthreads();
    if (tid == 0) {
        float m = lg[0];
        for (int c = 1; c < 21; ++c) m = fmaxf(m, lg[c]);
        float s = 0.0f;
        for (int c = 0; c < 21; ++c) { float e = expf(lg[c] - m); lg[c] = e; s += e; }
        ssum = s;
    }
    __syncthreads();
    if (tid < 20) {
        int c = tid + 1;
        int img = n / NPROP;
        float s = lg[c] / ssum;
        const float* pr = props + n * 4;
        float pw = pr[2] - pr[0], ph = pr[3] - pr[1];
        float px = pr[0] + pw * 0.5f, py = pr[1] + ph * 0.5f;
        const float* d = &bs[c * 4];
        float cx = px + d[0] * pw;
        float cy = py + d[1] * ph;
        float w = pw * expf(d[2]);
        float h = ph * expf(d[3]);
        float bx1 = cx - w * 0.5f, by1 = cy - h * 0.5f, bx2 = cx + w * 0.5f, by2 = cy + h * 0.5f;
        float Wi = (float)img_sizes[img * 2 + 1], Hi = (float)img_sizes[img * 2 + 0];
        bx1 = fminf(fmaxf(bx1, 0.f), Wi); by1 = fminf(fmaxf(by1, 0.f), Hi);
        bx2 = fminf(fmaxf(bx2, 0.f), Wi); by2 = fminf(fmaxf(by2, 0.f), Hi);
        int t = n * 20 + tid;                 // == img*NCAND + p*20 + (c-1)
        *(float4*)(cbox + (size_t)t * 4) = make_float4(bx1, by1, bx2, by2);
        csc[t] = s;
        bool valid = s > SCORE_T;
        unsigned int sb = __float_as_uint(s);
        int m = t - img * NCAND;
        ckey[t] = valid ? (((unsigned long long)sb << 32) | (unsigned int)(NCAND - 1 - m)) : 0ull;
    }
}

// ---------------- rank: uniform-j broadcast compares, 80 blocks (40 CUs/image) ----------------
// Restored: R9's fused rank on 2 blocks was LDS-BW-bound on 1 CU/image (53MB of
// LDS reads -> 174us). 40 blocks/image = 40x the aggregate LDS bandwidth.
__global__ __launch_bounds__(256) void rank_k(const float* __restrict__ cbox,
                                              const float* __restrict__ csc,
                                              const unsigned long long* __restrict__ ckey,
                                              float* __restrict__ sbox, float* __restrict__ ssc,
                                              int* __restrict__ sm, int* __restrict__ vcount) {
    int img = blockIdx.x / 40;
    int seg = blockIdx.x % 40;
    int base = img * NCAND;
    int lm = threadIdx.x & 63;
    int chunk = threadIdx.x >> 6;
    int m = seg * 64 + lm;
    __shared__ __align__(16) unsigned long long keys[NCAND];
    for (int j = threadIdx.x; j < NCAND; j += 256) keys[j] = ckey[base + j];
    unsigned long long mykey = ckey[base + m];
    float s = csc[base + m];
    bool valid = s > SCORE_T;
    __syncthreads();
    const ulonglong2* kp = (const ulonglong2*)&keys[chunk * 640];
    int r = 0;
#pragma unroll 4
    for (int j = 0; j < 320; ++j) {
        ulonglong2 kk = kp[j];
        r += (kk.x > mykey) ? 1 : 0;
        r += (kk.y > mykey) ? 1 : 0;
    }
    __shared__ int part[4][64];
    part[chunk][lm] = r;
    __syncthreads();
    if (chunk == 0) {
        int rank = part[0][lm] + part[1][lm] + part[2][lm] + part[3][lm];
        if (valid) {
            int o = base + rank;
            *(float4*)(sbox + (size_t)o * 4) = *(const float4*)(cbox + (size_t)(base + m) * 4);
            ssc[o] = s;
            sm[o] = m;
        }
    }
    int cnt = __syncthreads_count((chunk == 0) && valid);
    if (threadIdx.x == 0) atomicAdd(&vcount[img], cnt);
}

// ---------------- fused NMS + writer: one block per image, 1024 threads ----------------
// Phases 2+3 of R9's tail_k (verified correct there; they were cheap — only the
// rank phase was the 174us problem). One class per wave (classes w, w+16);
// block prefix-scan + top-100 emit. Replaces nms_k(40 blocks) + write_k(2).
__global__ __launch_bounds__(1024) void nms_write_k(const float* __restrict__ sbox,
                                                    const float* __restrict__ ssc,
                                                    const int* __restrict__ smg,
                                                    const int* __restrict__ vcount,
                                                    float* __restrict__ out) {
    const int img = blockIdx.x;
    const int tid = threadIdx.x;
    const int base = img * NCAND;

    __shared__ struct { float x1[20][128], y1[20][128], x2[20][128], y2[20][128]; } c;  // 40KB
    __shared__ short cpos[20][128];          // 5KB
    __shared__ unsigned char ckeepA[20][128];// 2.5KB
    __shared__ unsigned char smcls[NCAND];   // 2.5KB
    __shared__ unsigned char keepS[NCAND];   // 2.5KB
    __shared__ int scanA[1024], scanB[1024]; // 8KB

    const int V = vcount[img];
    for (int p = tid; p < V; p += 1024) smcls[p] = (unsigned char)(smg[base + p] % 20);
    __syncthreads();

    // per-class greedy NMS; wave w handles classes w, w+16
    const int wv = tid >> 6, lane = tid & 63;
    for (int ci = wv; ci < 20; ci += 16) {
        int cnt = 0;
        for (int p0 = 0; p0 < V; p0 += 64) {
            int p = p0 + lane;
            bool pred = (p < V) && (smcls[p] == (unsigned char)ci);
            unsigned long long mask = __ballot(pred);
            if (pred) {
                int idx = cnt + (int)__popcll(mask & ((1ull << lane) - 1ull));
                const float* bx = sbox + (size_t)(base + p) * 4;
                c.x1[ci][idx] = bx[0]; c.y1[ci][idx] = bx[1];
                c.x2[ci][idx] = bx[2]; c.y2[ci][idx] = bx[3];
                cpos[ci][idx] = (short)p;
            }
            cnt += (int)__popcll(mask);
        }
        for (int j2 = lane; j2 < 128; j2 += 64) ckeepA[ci][j2] = 1;
        for (int i = 0; i < cnt; ++i) {
            if (ckeepA[ci][i] == 0) continue;
            float X1 = c.x1[ci][i], Y1 = c.y1[ci][i];
            float X2 = c.x2[ci][i], Y2 = c.y2[ci][i];
            float ai = (X2 - X1) * (Y2 - Y1);
            for (int j2 = i + 1 + lane; j2 < cnt; j2 += 64) {
                if (ckeepA[ci][j2]) {
                    float xi1 = fmaxf(X1, c.x1[ci][j2]);
                    float yi1 = fmaxf(Y1, c.y1[ci][j2]);
                    float xi2 = fminf(X2, c.x2[ci][j2]);
                    float yi2 = fminf(Y2, c.y2[ci][j2]);
                    float inter = fmaxf(xi2 - xi1, 0.f) * fmaxf(yi2 - yi1, 0.f);
                    float aj = (c.x2[ci][j2] - c.x1[ci][j2]) * (c.y2[ci][j2] - c.y1[ci][j2]);
                    float iou = inter / (ai + aj - inter + 1e-9f);
                    if (iou > NMS_T) ckeepA[ci][j2] = 0;
                }
            }
        }
        for (int j2 = lane; j2 < cnt; j2 += 64) keepS[cpos[ci][j2]] = ckeepA[ci][j2];
    }
    __syncthreads();

    // zero outputs, block prefix-scan over keepS, emit top-100
    float* ob = out + img * MAXDET * 4;
    float* os = out + BATCH * MAXDET * 4 + img * MAXDET;
    float* ol = out + BATCH * MAXDET * 5 + img * MAXDET;
    for (int i = tid; i < MAXDET * 4; i += 1024) ob[i] = 0.0f;
    for (int i = tid; i < MAXDET; i += 1024) { os[i] = 0.0f; ol[i] = 0.0f; }
    int chunk = (V + 1023) >> 10;
    int lo = tid * chunk, hi = min(lo + chunk, V);
    int cnt2 = 0;
    for (int p = lo; p < hi; ++p) cnt2 += keepS[p];
    scanA[tid] = cnt2;
    __syncthreads();
    int* src = scanA; int* dst = scanB;
    for (int off = 1; off < 1024; off <<= 1) {
        int v = src[tid] + ((tid >= off) ? src[tid - off] : 0);
        dst[tid] = v;
        __syncthreads();
        int* t = src; src = dst; dst = t;
    }
    int r = (tid > 0) ? src[tid - 1] : 0;   // exclusive prefix
    for (int p = lo; p < hi; ++p) {
        if (keepS[p]) {
            if (r < MAXDET) {
                const float* bx = sbox + (size_t)(base + p) * 4;
                ob[r * 4 + 0] = bx[0]; ob[r * 4 + 1] = bx[1];
                ob[r * 4 + 2] = bx[2]; ob[r * 4 + 3] = bx[3];
                os[r] = ssc[base + p];
                ol[r] = (float)(smg[base + p] % 20 + 1);
            }
            ++r;
        }
    }
}

extern "C" void kernel_launch(void* const* d_in, const int* in_sizes, int n_in,
                              void* d_out, int out_size, void* d_ws, size_t ws_size,
                              hipStream_t stream) {
    const float* features  = (const float*)d_in[0];
    const float* proposals = (const float*)d_in[1];
    const int*   img_sizes = (const int*)d_in[2];
    const float* W1 = (const float*)d_in[3];
    const float* b1 = (const float*)d_in[4];
    const float* W2 = (const float*)d_in[5];
    const float* b2 = (const float*)d_in[6];
    const float* Wc = (const float*)d_in[7];
    const float* bc = (const float*)d_in[8];
    const float* Wb = (const float*)d_in[9];
    const float* bb = (const float*)d_in[10];
    float* out = (float*)d_out;

    float* ws = (float*)d_ws;
    float* roi   = ws;                        // 256*12544 = 3,211,264
    float* x1    = roi + 3211264;             // 262,144
    float* cpart = x1 + 262144;               // SPLIT1 * 262,144 (FC2 uses first 16 slices)
    float* featT = cpart;                     // aliases cpart: dead before FC1 writes it
    float* cbox  = cpart + (size_t)SPLIT1 * 262144;   // 20480
    float* csc   = cbox + 20480;              // 5120
    unsigned long long* ckey = (unsigned long long*)(csc + 5120);  // 5120 u64
    float* sbox  = csc + 5120 + 10240;        // 20480
    float* ssc   = sbox + 20480;              // 5120
    int*   smg   = (int*)(ssc + 5120);        // 5120
    int*   vcnt  = smg + 5120;                // 2

    hipLaunchKernelGGL(transpose_feat, dim3(32, 8, 2), dim3(256), 0, stream, features, featT);
    hipLaunchKernelGGL(roi_align_tr, dim3(NROI * 2), dim3(256), 0, stream, featT, proposals, roi);
    // FC1: 256 x 12544 -> 1024, tile 128x128, split-K=32 -> 512 blocks (2/CU)
    hipLaunchKernelGGL(gemm_tn_part, dim3(8, 2, SPLIT1), dim3(256), 0, stream, roi, W1, cpart, NROI, HID, FEAT_DIM);
    hipLaunchKernelGGL(reduce_bias_relu, dim3(1024), dim3(256), 0, stream, cpart, b1, x1, NROI, HID, SPLIT1);
    // FC2: 256 x 1024 -> 1024, split-K=16 (reduced inside heads_cand_k, order unchanged)
    hipLaunchKernelGGL(gemm_tn_part, dim3(8, 2, 16), dim3(256), 0, stream, x1, W2, cpart, NROI, HID, HID);
    hipLaunchKernelGGL(heads_cand_k, dim3(NROI), dim3(256), 0, stream, cpart, b2, Wc, bc, Wb, bb,
                       proposals, img_sizes, cbox, csc, ckey, vcnt);
    hipLaunchKernelGGL(rank_k, dim3(80), dim3(256), 0, stream, cbox, csc, ckey, sbox, ssc, smg, vcnt);
    hipLaunchKernelGGL(nms_write_k, dim3(BATCH), dim3(1024), 0, stream, sbox, ssc, smg, vcnt, out);
}